// Round 1
// baseline (357.944 us; speedup 1.0000x reference)
//
#include <hip/hip_runtime.h>
#include <stdint.h>

// ---------- types / helpers ----------
typedef __attribute__((ext_vector_type(8))) short short8;   // 8 x bf16 bits
typedef __attribute__((ext_vector_type(4))) float f32x4;

__device__ __forceinline__ unsigned short f2bf(float f) {
  unsigned u = __float_as_uint(f);
  u += 0x7fffu + ((u >> 16) & 1u);           // round-to-nearest-even
  return (unsigned short)(u >> 16);
}
__device__ __forceinline__ float bf2f(unsigned short u) {
  return __uint_as_float(((unsigned)u) << 16);
}

#define GLDS16(gp, lp)                                              \
  __builtin_amdgcn_global_load_lds(                                  \
      (const __attribute__((address_space(1))) void*)(gp),           \
      (__attribute__((address_space(3))) void*)(lp), 16, 0, 0)

// ---------- kernel 1: cast h (f32) -> hA (bf16) ----------
__global__ void __launch_bounds__(256) cast_h_kernel(const float* __restrict__ h,
                                                     unsigned short* __restrict__ hA,
                                                     long long total8) {
  long long i = (long long)blockIdx.x * 256 + threadIdx.x;
  if (i >= total8) return;
  const float4* p = (const float4*)(h + i * 8);
  float4 f0 = p[0], f1 = p[1];
  short8 r;
  r[0] = (short)f2bf(f0.x); r[1] = (short)f2bf(f0.y);
  r[2] = (short)f2bf(f0.z); r[3] = (short)f2bf(f0.w);
  r[4] = (short)f2bf(f1.x); r[5] = (short)f2bf(f1.y);
  r[6] = (short)f2bf(f1.z); r[7] = (short)f2bf(f1.w);
  *(short8*)(hA + i * 8) = r;
}

// ---------- kernel 2: BT[n][k] = bf16(W1[(n>=512? 512:0)+k][n&511]) ----------
// BT is [1024][512] bf16, n-major; GEMM computes P[m][n] = sum_k hA[m][k]*BT[n][k]
__global__ void __launch_bounds__(256) buildBT_kernel(const float* __restrict__ W1,
                                                      unsigned short* __restrict__ BT) {
  int t = blockIdx.x * 256 + threadIdx.x;   // 0..524287
  int n = t >> 9;
  int k = t & 511;
  float v = W1[((size_t)((n >> 9) * 512 + k)) * 512 + (size_t)(n & 511)];
  BT[t] = f2bf(v);
}

// ---------- kernel 3: GEMM  P[M][1024] (bf16) = hA[M][512] @ BT^T, +b1 on cols<512 ----------
// 128x128 tile, BK=32, 4 waves (2x2 of 64x64), mfma_f32_16x16x32_bf16
__global__ void __launch_bounds__(256) gemm_kernel(const unsigned short* __restrict__ hA,
                                                   const unsigned short* __restrict__ BT,
                                                   const float* __restrict__ b1,
                                                   unsigned short* __restrict__ P,
                                                   int M) {
  __shared__ unsigned short As[128 * 32];
  __shared__ unsigned short Bs[128 * 32];
  const int tid  = threadIdx.x;
  const int lane = tid & 63;
  const int wid  = tid >> 6;
  const int wr   = wid >> 1, wc = wid & 1;
  const int m0   = blockIdx.x * 128;
  const int n0   = blockIdx.y * 128;

  f32x4 acc[4][4];
#pragma unroll
  for (int i = 0; i < 4; ++i)
#pragma unroll
    for (int j = 0; j < 4; ++j) acc[i][j] = (f32x4){0.f, 0.f, 0.f, 0.f};

  const int srow   = tid >> 2;        // 0..63 (issue adds +64)
  const int kchunk = (tid & 3) * 8;   // k element offset of the 16B chunk

  for (int kt = 0; kt < 16; ++kt) {
    const int k0 = kt * 32;
#pragma unroll
    for (int q = 0; q < 2; ++q) {
      const int row  = q * 64 + srow;
      const int grow = m0 + row;
      if (grow < M) {
        const unsigned short* gA = hA + (size_t)grow * 512 + (size_t)(k0 + kchunk);
        GLDS16(gA, &As[row * 32 + kchunk]);
      }
      const unsigned short* gB = BT + (size_t)(n0 + row) * 512 + (size_t)(k0 + kchunk);
      GLDS16(gB, &Bs[row * 32 + kchunk]);
    }
    __syncthreads();   // drains vmcnt: tiles staged

    const int kk = (lane >> 4) * 8;
    const int lr = lane & 15;
    short8 aF[4], bF[4];
#pragma unroll
    for (int i = 0; i < 4; ++i)
      aF[i] = *(const short8*)&As[(wr * 64 + i * 16 + lr) * 32 + kk];
#pragma unroll
    for (int j = 0; j < 4; ++j)
      bF[j] = *(const short8*)&Bs[(wc * 64 + j * 16 + lr) * 32 + kk];
#pragma unroll
    for (int i = 0; i < 4; ++i)
#pragma unroll
      for (int j = 0; j < 4; ++j)
        acc[i][j] = __builtin_amdgcn_mfma_f32_16x16x32_bf16(aF[i], bF[j], acc[i][j], 0, 0, 0);
    __syncthreads();   // all reads done before next stage overwrites
  }

  // epilogue: + b1 (cols < 512 only), store bf16
  const int lr    = lane & 15;
  const int rbase = (lane >> 4) * 4;
#pragma unroll
  for (int j = 0; j < 4; ++j) {
    const int col  = n0 + wc * 64 + j * 16 + lr;
    const float bias = (col < 512) ? b1[col] : 0.0f;
#pragma unroll
    for (int i = 0; i < 4; ++i) {
      const int rowb = m0 + wr * 64 + i * 16 + rbase;
#pragma unroll
      for (int r = 0; r < 4; ++r) {
        const int row = rowb + r;
        if (row < M) P[(size_t)row * 1024 + col] = f2bf(acc[i][j][r] + bias);
      }
    }
  }
}

// ---------- kernel 4: per-edge score ----------
// score[e] = b2 + sum_j relu(P[src][j] + P[dst][512+j]) * W2[j]
__global__ void __launch_bounds__(256) edge_kernel(const unsigned short* __restrict__ P,
                                                   const int* __restrict__ src,
                                                   const int* __restrict__ dst,
                                                   const float* __restrict__ W2,
                                                   const float* __restrict__ b2,
                                                   float* __restrict__ out,
                                                   int E) {
  const int gw   = (blockIdx.x * 256 + threadIdx.x) >> 6;   // global wave = edge
  const int lane = threadIdx.x & 63;
  if (gw >= E) return;
  const int s = src[gw];
  const int d = dst[gw];
  const short8 va = *(const short8*)(P + (size_t)s * 1024 + lane * 8);
  const short8 vb = *(const short8*)(P + (size_t)d * 1024 + 512 + lane * 8);
  const float4 w0 = *(const float4*)(W2 + lane * 8);
  const float4 w1 = *(const float4*)(W2 + lane * 8 + 4);
  float a = 0.f, x;
  x = bf2f((unsigned short)va[0]) + bf2f((unsigned short)vb[0]); a += fmaxf(x, 0.f) * w0.x;
  x = bf2f((unsigned short)va[1]) + bf2f((unsigned short)vb[1]); a += fmaxf(x, 0.f) * w0.y;
  x = bf2f((unsigned short)va[2]) + bf2f((unsigned short)vb[2]); a += fmaxf(x, 0.f) * w0.z;
  x = bf2f((unsigned short)va[3]) + bf2f((unsigned short)vb[3]); a += fmaxf(x, 0.f) * w0.w;
  x = bf2f((unsigned short)va[4]) + bf2f((unsigned short)vb[4]); a += fmaxf(x, 0.f) * w1.x;
  x = bf2f((unsigned short)va[5]) + bf2f((unsigned short)vb[5]); a += fmaxf(x, 0.f) * w1.y;
  x = bf2f((unsigned short)va[6]) + bf2f((unsigned short)vb[6]); a += fmaxf(x, 0.f) * w1.z;
  x = bf2f((unsigned short)va[7]) + bf2f((unsigned short)vb[7]); a += fmaxf(x, 0.f) * w1.w;
#pragma unroll
  for (int o = 32; o > 0; o >>= 1) a += __shfl_down(a, o);
  if (lane == 0) out[gw] = a + b2[0];
}

// ---------- launcher ----------
extern "C" void kernel_launch(void* const* d_in, const int* in_sizes, int n_in,
                              void* d_out, int out_size, void* d_ws, size_t ws_size,
                              hipStream_t stream) {
  const float* h  = (const float*)d_in[0];
  const int*   src = (const int*)d_in[1];
  const int*   dst = (const int*)d_in[2];
  const float* W1 = (const float*)d_in[3];
  const float* b1 = (const float*)d_in[4];
  const float* W2 = (const float*)d_in[5];
  const float* b2 = (const float*)d_in[6];
  float* out = (float*)d_out;

  const int M = in_sizes[0] / 512;   // 100000 nodes
  const int E = in_sizes[1];         // 160000 edges

  char* ws = (char*)d_ws;
  unsigned short* hA = (unsigned short*)ws;                          // M*512 bf16
  size_t off = (((size_t)M * 512 * 2) + 255) & ~(size_t)255;
  unsigned short* BT = (unsigned short*)(ws + off);                  // 1024*512 bf16
  off += (size_t)1024 * 512 * 2;
  unsigned short* P = (unsigned short*)(ws + off);                   // M*1024 bf16

  const long long total8 = (long long)M * 512 / 8;
  cast_h_kernel<<<(int)((total8 + 255) / 256), 256, 0, stream>>>(h, hA, total8);
  buildBT_kernel<<<2048, 256, 0, stream>>>(W1, BT);
  dim3 g((M + 127) / 128, 8);
  gemm_kernel<<<g, 256, 0, stream>>>(hA, BT, b1, P, M);
  edge_kernel<<<(E + 3) / 4, 256, 0, stream>>>(P, src, dst, W2, b2, out, E);
}

// Round 2
// 264.952 us; speedup vs baseline: 1.3510x; 1.3510x over previous
//
#include <hip/hip_runtime.h>
#include <stdint.h>

// ---------- types / helpers ----------
typedef __attribute__((ext_vector_type(8))) short short8;   // 8 x bf16 bits
typedef __attribute__((ext_vector_type(4))) float f32x4;

__device__ __forceinline__ unsigned short f2bf(float f) {
  unsigned u = __float_as_uint(f);
  u += 0x7fffu + ((u >> 16) & 1u);           // round-to-nearest-even
  return (unsigned short)(u >> 16);
}
__device__ __forceinline__ float bf2f(unsigned short u) {
  return __uint_as_float(((unsigned)u) << 16);
}

#define GLDS16(gp, lp)                                              \
  __builtin_amdgcn_global_load_lds(                                  \
      (const __attribute__((address_space(1))) void*)(gp),           \
      (__attribute__((address_space(3))) void*)(lp), 16, 0, 0)

// ---------- kernel 1: cast h (f32) -> hA (bf16) ----------
__global__ void __launch_bounds__(256) cast_h_kernel(const float* __restrict__ h,
                                                     unsigned short* __restrict__ hA,
                                                     long long total8) {
  long long i = (long long)blockIdx.x * 256 + threadIdx.x;
  if (i >= total8) return;
  const float4* p = (const float4*)(h + i * 8);
  float4 f0 = p[0], f1 = p[1];
  short8 r;
  r[0] = (short)f2bf(f0.x); r[1] = (short)f2bf(f0.y);
  r[2] = (short)f2bf(f0.z); r[3] = (short)f2bf(f0.w);
  r[4] = (short)f2bf(f1.x); r[5] = (short)f2bf(f1.y);
  r[6] = (short)f2bf(f1.z); r[7] = (short)f2bf(f1.w);
  *(short8*)(hA + i * 8) = r;
}

// ---------- kernel 2: BT[n][k] = bf16(W1[(n>=512? 512:0)+k][n&511]) ----------
__global__ void __launch_bounds__(256) buildBT_kernel(const float* __restrict__ W1,
                                                      unsigned short* __restrict__ BT) {
  int t = blockIdx.x * 256 + threadIdx.x;   // 0..524287
  int n = t >> 9;
  int k = t & 511;
  float v = W1[((size_t)((n >> 9) * 512 + k)) * 512 + (size_t)(n & 511)];
  BT[t] = f2bf(v);
}

// ---------- kernel 3: GEMM  P[M][1024](bf16) = hA[M][512] @ BT^T (+b1 cols<512) ----------
// 128x128 tile, BK=64, 4 waves (2x2 of 64x64), slot-XOR LDS swizzle, LDS-repack epilogue.
__global__ void __launch_bounds__(256) gemm_kernel(const unsigned short* __restrict__ hA,
                                                   const unsigned short* __restrict__ BT,
                                                   const float* __restrict__ b1,
                                                   unsigned short* __restrict__ P,
                                                   int M) {
  __shared__ unsigned short As[128 * 64];   // 16 KB
  __shared__ unsigned short Bs[128 * 64];   // 16 KB

  // --- XCD-chunked block swizzle; logical order: n-tile fastest within an A strip ---
  const int nwg = gridDim.x;                // Mtiles*8, divisible by 8
  const int cpx = nwg >> 3;
  const int wg  = (blockIdx.x & 7) * cpx + (blockIdx.x >> 3);
  const int nt  = wg & 7;
  const int mt  = wg >> 3;
  const int m0  = mt * 128;
  const int n0  = nt * 128;

  const int tid  = threadIdx.x;
  const int lane = tid & 63;
  const int wid  = tid >> 6;
  const int wr   = wid >> 1, wc = wid & 1;

  f32x4 acc[4][4];
#pragma unroll
  for (int i = 0; i < 4; ++i)
#pragma unroll
    for (int j = 0; j < 4; ++j) acc[i][j] = (f32x4){0.f, 0.f, 0.f, 0.f};

  const int srow = tid >> 3;     // 0..31 per issue
  const int slot = tid & 7;      // physical 16B slot within 128B row

  const int lr = lane & 15;
  const int g  = lane >> 4;

  for (int kt = 0; kt < 8; ++kt) {
    const int k0 = kt * 64;
#pragma unroll
    for (int q = 0; q < 4; ++q) {
      const int row = q * 32 + srow;
      const int gk  = k0 + ((slot ^ (row & 7)) << 3);   // inverse-swizzled source
      const int ga  = m0 + row;
      if (ga < M) GLDS16(hA + (size_t)ga * 512 + gk, &As[row * 64 + slot * 8]);
      GLDS16(BT + (size_t)(n0 + row) * 512 + gk, &Bs[row * 64 + slot * 8]);
    }
    __syncthreads();   // drains vmcnt: tiles staged

    short8 aF[2][4], bF[2][4];
#pragma unroll
    for (int s = 0; s < 2; ++s) {
#pragma unroll
      for (int i = 0; i < 4; ++i) {
        const int row = wr * 64 + i * 16 + lr;
        const int p   = (s * 4 + g) ^ (row & 7);
        aF[s][i] = *(const short8*)&As[row * 64 + p * 8];
      }
#pragma unroll
      for (int j = 0; j < 4; ++j) {
        const int row = wc * 64 + j * 16 + lr;
        const int p   = (s * 4 + g) ^ (row & 7);
        bF[s][j] = *(const short8*)&Bs[row * 64 + p * 8];
      }
    }
#pragma unroll
    for (int s = 0; s < 2; ++s)
#pragma unroll
      for (int i = 0; i < 4; ++i)
#pragma unroll
        for (int j = 0; j < 4; ++j)
          acc[i][j] = __builtin_amdgcn_mfma_f32_16x16x32_bf16(aF[s][i], bF[s][j], acc[i][j], 0, 0, 0);
    __syncthreads();   // reads done before next stage overwrites
  }

  // --- epilogue: bias + bf16 + LDS repack for coalesced stores ---
  float bias[4];
#pragma unroll
  for (int j = 0; j < 4; ++j) {
    const int col = n0 + wc * 64 + j * 16 + lr;
    bias[j] = (col < 512) ? b1[col] : 0.0f;
  }
  unsigned short* Ls = As;   // 32 x 128 bf16 = 8 KB, reuse
  const int lrow2 = tid >> 3;            // 0..31
  const int c0    = (tid & 7) * 16;      // 16 elems = 32B per thread
  const int grB   = m0 + (lrow2 >> 4) * 64;
#pragma unroll
  for (int i = 0; i < 4; ++i) {
#pragma unroll
    for (int j = 0; j < 4; ++j) {
      const int col  = wc * 64 + j * 16 + lr;
      const int lrow = wr * 16 + g * 4;
#pragma unroll
      for (int r = 0; r < 4; ++r)
        Ls[(lrow + r) * 128 + col] = f2bf(acc[i][j][r] + bias[j]);
    }
    __syncthreads();
    const int gr = grB + i * 16 + (lrow2 & 15);
    if (gr < M) {
      const short8 v0 = *(const short8*)&Ls[lrow2 * 128 + c0];
      const short8 v1 = *(const short8*)&Ls[lrow2 * 128 + c0 + 8];
      *(short8*)(P + (size_t)gr * 1024 + n0 + c0)     = v0;
      *(short8*)(P + (size_t)gr * 1024 + n0 + c0 + 8) = v1;
    }
    __syncthreads();
  }
}

// ---------- kernel 4: per-edge score ----------
__global__ void __launch_bounds__(256) edge_kernel(const unsigned short* __restrict__ P,
                                                   const int* __restrict__ src,
                                                   const int* __restrict__ dst,
                                                   const float* __restrict__ W2,
                                                   const float* __restrict__ b2,
                                                   float* __restrict__ out,
                                                   int E) {
  const int gw   = (blockIdx.x * 256 + threadIdx.x) >> 6;   // global wave = edge
  const int lane = threadIdx.x & 63;
  if (gw >= E) return;
  const int s = src[gw];
  const int d = dst[gw];
  const short8 va = *(const short8*)(P + (size_t)s * 1024 + lane * 8);
  const short8 vb = *(const short8*)(P + (size_t)d * 1024 + 512 + lane * 8);
  const float4 w0 = *(const float4*)(W2 + lane * 8);
  const float4 w1 = *(const float4*)(W2 + lane * 8 + 4);
  float a = 0.f, x;
  x = bf2f((unsigned short)va[0]) + bf2f((unsigned short)vb[0]); a += fmaxf(x, 0.f) * w0.x;
  x = bf2f((unsigned short)va[1]) + bf2f((unsigned short)vb[1]); a += fmaxf(x, 0.f) * w0.y;
  x = bf2f((unsigned short)va[2]) + bf2f((unsigned short)vb[2]); a += fmaxf(x, 0.f) * w0.z;
  x = bf2f((unsigned short)va[3]) + bf2f((unsigned short)vb[3]); a += fmaxf(x, 0.f) * w0.w;
  x = bf2f((unsigned short)va[4]) + bf2f((unsigned short)vb[4]); a += fmaxf(x, 0.f) * w1.x;
  x = bf2f((unsigned short)va[5]) + bf2f((unsigned short)vb[5]); a += fmaxf(x, 0.f) * w1.y;
  x = bf2f((unsigned short)va[6]) + bf2f((unsigned short)vb[6]); a += fmaxf(x, 0.f) * w1.z;
  x = bf2f((unsigned short)va[7]) + bf2f((unsigned short)vb[7]); a += fmaxf(x, 0.f) * w1.w;
#pragma unroll
  for (int o = 32; o > 0; o >>= 1) a += __shfl_down(a, o);
  if (lane == 0) out[gw] = a + b2[0];
}

// ---------- launcher ----------
extern "C" void kernel_launch(void* const* d_in, const int* in_sizes, int n_in,
                              void* d_out, int out_size, void* d_ws, size_t ws_size,
                              hipStream_t stream) {
  const float* h  = (const float*)d_in[0];
  const int*   src = (const int*)d_in[1];
  const int*   dst = (const int*)d_in[2];
  const float* W1 = (const float*)d_in[3];
  const float* b1 = (const float*)d_in[4];
  const float* W2 = (const float*)d_in[5];
  const float* b2 = (const float*)d_in[6];
  float* out = (float*)d_out;

  const int M = in_sizes[0] / 512;   // 100000 nodes
  const int E = in_sizes[1];         // 160000 edges

  char* ws = (char*)d_ws;
  unsigned short* hA = (unsigned short*)ws;                          // M*512 bf16
  size_t off = (((size_t)M * 512 * 2) + 255) & ~(size_t)255;
  unsigned short* BT = (unsigned short*)(ws + off);                  // 1024*512 bf16
  off += (size_t)1024 * 512 * 2;
  unsigned short* P = (unsigned short*)(ws + off);                   // M*1024 bf16

  const long long total8 = (long long)M * 512 / 8;
  cast_h_kernel<<<(int)((total8 + 255) / 256), 256, 0, stream>>>(h, hA, total8);
  buildBT_kernel<<<2048, 256, 0, stream>>>(W1, BT);
  const int Mtiles = (M + 127) / 128;
  gemm_kernel<<<Mtiles * 8, 256, 0, stream>>>(hA, BT, b1, P, M);
  edge_kernel<<<(E + 3) / 4, 256, 0, stream>>>(P, src, dst, W2, b2, out, E);
}